// Round 7
// baseline (173963.452 us; speedup 1.0000x reference)
//
#include <hip/hip_runtime.h>

typedef __attribute__((ext_vector_type(4))) float f4;
using u32 = unsigned int;

constexpr int NB_ = 16;    // batch
constexpr int NS_ = 512;   // seq len
constexpr int ND_ = 1024;  // input dim
constexpr int NH_ = 512;   // hidden
constexpr int NSP_ = 8;    // speakers
constexpr int NH2_ = 256;  // head hidden
constexpr int HP = 520;    // padded fp32 LDS row (130 f4)

struct Params {
  const float *utt;
  const float *pg_wih, *pg_whh, *gg_wih, *gg_whh, *eg_wih, *eg_whh, *out_w1;
  const float *gixp, *gixg;   // precomputed x-projections [B*S][1536] fp32
  const float *init_party, *init_emotion;
  const float *pg_bih, *pg_bhh, *gg_bih, *gg_bhh, *eg_bih, *eg_bhh;
  const float *ln_g, *ln_b, *out_b1, *out_ln_g, *out_ln_b, *out_w2, *out_b2;
  const int *spk;
  float *party_pre;  // [2][B][H] raw pg output (pre-LN), parity t&1
  float *g_new;      // [B][H]    raw gg output
  float *e_out;      // [2][B][H] raw eg output, parity t&1
  float *glob;       // [B][SP][H] post-LN (or raw init) global states
  float *h1buf;      // [B][H2] relu(e@W1+b1)
  double *sums;      // [3 groups][2 par][16 b][2] = 192 doubles
  u32 *bar;          // [counter, generation]
  float *out;        // [B][S]
};

__device__ __forceinline__ double sigm_d(double x) { return 1.0 / (1.0 + exp(-x)); }
__device__ __forceinline__ int sidx(int g, int par, int b, int c) {
  return ((g * 2 + par) * 16 + b) * 2 + c;
}
__device__ __forceinline__ double dot4d(f4 a, f4 w) {
  return ((double)a.x * w.x + (double)a.y * w.y) + ((double)a.z * w.z + (double)a.w * w.w);
}

struct __align__(16) Smem {
  float hA[NB_][HP];            // operand 1 (LN'd party / glob row / LN'd emo / e_out for head)
  float hB[NB_][HP];            // operand 2 (eg: LN'd spk_state)
  double red[8][2][8][4];       // [jj][bg][b8][r,z,pn,ph] wave-reduced partials
  double redH[16][2][8];        // head partials [ci][bg][b8]
  double stats[2][NB_][2];      // {mu, rstd}
  int spk[NB_];
};

// device-scope generation barrier (144 blocks, 1/CU co-resident on 256 CUs)
__device__ __forceinline__ void gbar(u32* cnt, u32* gen, u32 nb) {
  __syncthreads();
  if (threadIdx.x == 0) {
    __threadfence();
    u32 g = __hip_atomic_load(gen, __ATOMIC_RELAXED, __HIP_MEMORY_SCOPE_AGENT);
    u32 a = __hip_atomic_fetch_add(cnt, 1u, __ATOMIC_ACQ_REL, __HIP_MEMORY_SCOPE_AGENT);
    if (a == nb - 1u) {
      __hip_atomic_store(cnt, 0u, __ATOMIC_RELAXED, __HIP_MEMORY_SCOPE_AGENT);
      __hip_atomic_fetch_add(gen, 1u, __ATOMIC_RELEASE, __HIP_MEMORY_SCOPE_AGENT);
    } else {
      while (__hip_atomic_load(gen, __ATOMIC_ACQUIRE, __HIP_MEMORY_SCOPE_AGENT) == g)
        __builtin_amdgcn_s_sleep(1);
    }
    __threadfence();
  }
  __syncthreads();
}

// phase A: party GRU (is_pg) or global GRU (!is_pg); block owns 8 j-columns (jj0 base).
// K=1024 unified: [0,512) h via wih-ctx cols; [512,1024) h via whh. x-part precomputed in gix.
__device__ void pg_gg_step(const Params& p, Smem& sm, int t, int jj0, bool is_pg) {
  const int tid = threadIdx.x;
  const float* wih = is_pg ? p.pg_wih : p.gg_wih;
  const float* whh = is_pg ? p.pg_whh : p.gg_whh;
  const float* bih = is_pg ? p.pg_bih : p.gg_bih;
  const float* bhh = is_pg ? p.pg_bhh : p.gg_bhh;
  const float* gix = is_pg ? p.gixp : p.gixg;
  const int g = is_pg ? 0 : 1;

  if (!is_pg) {
    if (tid < NB_) sm.spk[tid] = p.spk[tid * NS_ + t];
  } else if (t > 0 && tid < NB_) {
    double s = p.sums[sidx(0, (t - 1) & 1, tid, 0)];
    double q = p.sums[sidx(0, (t - 1) & 1, tid, 1)];
    double mu = s * (1.0 / NH_), var = q * (1.0 / NH_) - mu * mu;
    sm.stats[0][tid][0] = mu; sm.stats[0][tid][1] = 1.0 / sqrt(var + 1e-5);
  }
  __syncthreads();

  // stage h operand (fp32 values, LN applied in fp64)
  const float* prev = p.party_pre + (size_t)((t - 1) & 1) * NB_ * NH_;
  for (int idx = tid; idx < NB_ * NH_ / 4; idx += 512) {
    int b = idx >> 7, k = (idx & 127) * 4;
    f4 v;
    if (is_pg) {
      if (t == 0) v = *(const f4*)&p.init_party[k];
      else {
        f4 pv = *(const f4*)&prev[b * NH_ + k];
        f4 g4 = *(const f4*)&p.ln_g[k], b4 = *(const f4*)&p.ln_b[k];
        double mu = sm.stats[0][b][0], rs = sm.stats[0][b][1];
        v.x = (float)(((double)pv.x - mu) * rs * g4.x + b4.x);
        v.y = (float)(((double)pv.y - mu) * rs * g4.y + b4.y);
        v.z = (float)(((double)pv.z - mu) * rs * g4.z + b4.z);
        v.w = (float)(((double)pv.w - mu) * rs * g4.w + b4.w);
      }
    } else {
      v = *(const f4*)&p.glob[(size_t)(b * NSP_ + sm.spk[b]) * NH_ + k];
    }
    *(f4*)&sm.hA[b][k] = v;
  }
  __syncthreads();

  // dot phase: thread = (jj=wave, bg, kc); weight f4 loaded once, FMA'd over 8 b from LDS.
  // interleaved K: q = kc + 32*i -> coalesced W loads, conflict-free LDS reads.
  {
    int jj = tid >> 6, lane = tid & 63, bg = lane >> 5, kc = lane & 31;
    int j = jj0 + jj;
    const f4* Wr_w = (const f4*)(wih + (size_t)j * 1536 + 1024);
    const f4* Wz_w = (const f4*)(wih + (size_t)(512 + j) * 1536 + 1024);
    const f4* Wn_w = (const f4*)(wih + (size_t)(1024 + j) * 1536 + 1024);
    const f4* Wr_h = (const f4*)(whh + (size_t)j * 512);
    const f4* Wz_h = (const f4*)(whh + (size_t)(512 + j) * 512);
    const f4* Wn_h = (const f4*)(whh + (size_t)(1024 + j) * 512);
    const f4* H = (const f4*)&sm.hA[0][0];
    double ar[8] = {}, az[8] = {}, apn[8] = {}, aph[8] = {};
#pragma unroll
    for (int i = 0; i < 8; ++i) {
      int q = kc + 32 * i;
      f4 wr, wz, wn; int hq;
      if (i < 4) { wr = Wr_w[q]; wz = Wz_w[q]; wn = Wn_w[q]; hq = q; }
      else       { wr = Wr_h[q - 128]; wz = Wz_h[q - 128]; wn = Wn_h[q - 128]; hq = q - 128; }
#pragma unroll
      for (int b = 0; b < 8; ++b) {
        f4 a = H[(bg * 8 + b) * (HP / 4) + hq];
        ar[b] += dot4d(a, wr); az[b] += dot4d(a, wz);
        if (i < 4) apn[b] += dot4d(a, wn); else aph[b] += dot4d(a, wn);
      }
    }
#pragma unroll
    for (int b = 0; b < 8; ++b) {
      double r = ar[b], z = az[b], pn = apn[b], ph = aph[b];
#pragma unroll
      for (int m = 1; m <= 16; m <<= 1) {
        r += __shfl_xor(r, m); z += __shfl_xor(z, m);
        pn += __shfl_xor(pn, m); ph += __shfl_xor(ph, m);
      }
      if (kc == 0) {
        sm.red[jj][bg][b][0] = r; sm.red[jj][bg][b][1] = z;
        sm.red[jj][bg][b][2] = pn; sm.red[jj][bg][b][3] = ph;
      }
    }
  }
  __syncthreads();

  // gate math (fp64): 128 threads = (b 16, jj 8)
  if (tid < 128) {
    int b = tid >> 3, jj = tid & 7, j = jj0 + jj;
    const double* rd = sm.red[jj][b >> 3][b & 7];
    const float* gx = gix + (size_t)(b * NS_ + t) * 1536;
    double r = sigm_d(rd[0] + (double)gx[j] + (double)bih[j] + (double)bhh[j]);
    double z = sigm_d(rd[1] + (double)gx[512 + j] + (double)bih[512 + j] + (double)bhh[512 + j]);
    double inn = rd[2] + (double)gx[1024 + j] + (double)bih[1024 + j];
    double hn  = rd[3] + (double)bhh[1024 + j];
    double n = tanh(inn + r * hn);
    double hp = (double)sm.hA[b][j];
    double hv = (1.0 - z) * n + z * hp;
    float hf = (float)hv;
    float* dst = is_pg ? (p.party_pre + (size_t)(t & 1) * NB_ * NH_) : p.g_new;
    dst[b * NH_ + j] = hf;
    double s1 = (double)hf, s2 = (double)hf * (double)hf;
#pragma unroll
    for (int m = 1; m <= 4; m <<= 1) { s1 += __shfl_xor(s1, m); s2 += __shfl_xor(s2, m); }
    if (jj == 0) {
      atomicAdd(&p.sums[sidx(g, t & 1, b, 0)], s1);
      atomicAdd(&p.sums[sidx(g, t & 1, b, 1)], s2);
    }
  }
}

// phase B: emotion GRU; block owns 8 j. K=1536: [0,512) emo/wih; [512,1024) spk/wih; [1024,1536) emo/whh
__device__ void eg_step(const Params& p, Smem& sm, int t, int jj0) {
  const int tid = threadIdx.x;
  if (t > 0 && tid < NB_) {
    double s = p.sums[sidx(2, (t - 1) & 1, tid, 0)];
    double q = p.sums[sidx(2, (t - 1) & 1, tid, 1)];
    double mu = s * (1.0 / NH_), var = q * (1.0 / NH_) - mu * mu;
    sm.stats[0][tid][0] = mu; sm.stats[0][tid][1] = 1.0 / sqrt(var + 1e-5);
  }
  if (tid >= NB_ && tid < 2 * NB_) {
    int b = tid - NB_;
    double s = p.sums[sidx(1, t & 1, b, 0)];
    double q = p.sums[sidx(1, t & 1, b, 1)];
    double mu = s * (1.0 / NH_), var = q * (1.0 / NH_) - mu * mu;
    sm.stats[1][b][0] = mu; sm.stats[1][b][1] = 1.0 / sqrt(var + 1e-5);
  }
  __syncthreads();
  const float* eprev = p.e_out + (size_t)((t - 1) & 1) * NB_ * NH_;
  for (int idx = tid; idx < NB_ * NH_ / 2; idx += 512) {
    int half = idx >= NB_ * NH_ / 4;
    int r4 = idx & (NB_ * NH_ / 4 - 1);
    int b = r4 >> 7, k = (r4 & 127) * 4;
    f4 g4 = *(const f4*)&p.ln_g[k], b4 = *(const f4*)&p.ln_b[k];
    if (!half) {
      f4 v;
      if (t == 0) v = *(const f4*)&p.init_emotion[k];
      else {
        f4 pv = *(const f4*)&eprev[b * NH_ + k];
        double mu = sm.stats[0][b][0], rs = sm.stats[0][b][1];
        v.x = (float)(((double)pv.x - mu) * rs * g4.x + b4.x);
        v.y = (float)(((double)pv.y - mu) * rs * g4.y + b4.y);
        v.z = (float)(((double)pv.z - mu) * rs * g4.z + b4.z);
        v.w = (float)(((double)pv.w - mu) * rs * g4.w + b4.w);
      }
      *(f4*)&sm.hA[b][k] = v;
    } else {
      f4 pv = *(const f4*)&p.g_new[b * NH_ + k];
      double mu = sm.stats[1][b][0], rs = sm.stats[1][b][1];
      f4 v;
      v.x = (float)(((double)pv.x - mu) * rs * g4.x + b4.x);
      v.y = (float)(((double)pv.y - mu) * rs * g4.y + b4.y);
      v.z = (float)(((double)pv.z - mu) * rs * g4.z + b4.z);
      v.w = (float)(((double)pv.w - mu) * rs * g4.w + b4.w);
      *(f4*)&sm.hB[b][k] = v;
    }
  }
  __syncthreads();
  {
    int jj = tid >> 6, lane = tid & 63, bg = lane >> 5, kc = lane & 31;
    int j = jj0 + jj;
    const f4* Wr_w = (const f4*)(p.eg_wih + (size_t)j * 1024);
    const f4* Wz_w = (const f4*)(p.eg_wih + (size_t)(512 + j) * 1024);
    const f4* Wn_w = (const f4*)(p.eg_wih + (size_t)(1024 + j) * 1024);
    const f4* Wr_h = (const f4*)(p.eg_whh + (size_t)j * 512);
    const f4* Wz_h = (const f4*)(p.eg_whh + (size_t)(512 + j) * 512);
    const f4* Wn_h = (const f4*)(p.eg_whh + (size_t)(1024 + j) * 512);
    const f4* HA = (const f4*)&sm.hA[0][0];
    const f4* HB = (const f4*)&sm.hB[0][0];
    double ar[8] = {}, az[8] = {}, apn[8] = {}, aph[8] = {};
#pragma unroll
    for (int i = 0; i < 12; ++i) {
      int q = kc + 32 * i;
      f4 wr, wz, wn; const f4* Ab; int hq;
      if (i < 8) { wr = Wr_w[q]; wz = Wz_w[q]; wn = Wn_w[q]; }
      else       { wr = Wr_h[q - 256]; wz = Wz_h[q - 256]; wn = Wn_h[q - 256]; }
      if (i < 4)      { Ab = HA; hq = q; }
      else if (i < 8) { Ab = HB; hq = q - 128; }
      else            { Ab = HA; hq = q - 256; }
#pragma unroll
      for (int b = 0; b < 8; ++b) {
        f4 a = Ab[(bg * 8 + b) * (HP / 4) + hq];
        ar[b] += dot4d(a, wr); az[b] += dot4d(a, wz);
        if (i < 8) apn[b] += dot4d(a, wn); else aph[b] += dot4d(a, wn);
      }
    }
#pragma unroll
    for (int b = 0; b < 8; ++b) {
      double r = ar[b], z = az[b], pn = apn[b], ph = aph[b];
#pragma unroll
      for (int m = 1; m <= 16; m <<= 1) {
        r += __shfl_xor(r, m); z += __shfl_xor(z, m);
        pn += __shfl_xor(pn, m); ph += __shfl_xor(ph, m);
      }
      if (kc == 0) {
        sm.red[jj][bg][b][0] = r; sm.red[jj][bg][b][1] = z;
        sm.red[jj][bg][b][2] = pn; sm.red[jj][bg][b][3] = ph;
      }
    }
  }
  __syncthreads();
  if (tid < 128) {
    int b = tid >> 3, jj = tid & 7, j = jj0 + jj;
    const double* rd = sm.red[jj][b >> 3][b & 7];
    double r = sigm_d(rd[0] + (double)p.eg_bih[j] + (double)p.eg_bhh[j]);
    double z = sigm_d(rd[1] + (double)p.eg_bih[512 + j] + (double)p.eg_bhh[512 + j]);
    double inn = rd[2] + (double)p.eg_bih[1024 + j];
    double hn  = rd[3] + (double)p.eg_bhh[1024 + j];
    double n = tanh(inn + r * hn);
    double hp = (double)sm.hA[b][j];
    double hv = (1.0 - z) * n + z * hp;
    float hf = (float)hv;
    p.e_out[(size_t)(t & 1) * NB_ * NH_ + b * NH_ + j] = hf;
    double s1 = (double)hf, s2 = (double)hf * (double)hf;
#pragma unroll
    for (int m = 1; m <= 4; m <<= 1) { s1 += __shfl_xor(s1, m); s2 += __shfl_xor(s2, m); }
    if (jj == 0) {
      atomicAdd(&p.sums[sidx(2, t & 1, b, 0)], s1);
      atomicAdd(&p.sums[sidx(2, t & 1, b, 1)], s2);
    }
  }
}

// phase B: glob[b][spk_t] <- LN(g_new); zero next-parity pg/gg sums
__device__ void wb_step(const Params& p, int t, int b) {
  const int tid = threadIdx.x;
  int spv = p.spk[b * NS_ + t];
  double s = p.sums[sidx(1, t & 1, b, 0)], q = p.sums[sidx(1, t & 1, b, 1)];
  double mu = s * (1.0 / NH_), var = q * (1.0 / NH_) - mu * mu, rs = 1.0 / sqrt(var + 1e-5);
  if (tid < NH_)
    p.glob[(size_t)(b * NSP_ + spv) * NH_ + tid] =
        (float)(((double)p.g_new[b * NH_ + tid] - mu) * rs * p.ln_g[tid] + p.ln_b[tid]);
  if (tid == 0) {
    int par = (t + 1) & 1;
    p.sums[sidx(0, par, b, 0)] = 0.0; p.sums[sidx(0, par, b, 1)] = 0.0;
    p.sums[sidx(1, par, b, 0)] = 0.0; p.sums[sidx(1, par, b, 1)] = 0.0;
  }
}

// phase A: h1[b][ct*16..+16] = relu(e_out(th) @ W1^T + b1); block owns 16 c
__device__ void head_step(const Params& p, Smem& sm, int th, int ct) {
  const int tid = threadIdx.x;
  const float* er = p.e_out + (size_t)(th & 1) * NB_ * NH_;
  for (int idx = tid; idx < NB_ * NH_ / 4; idx += 512) {
    int b = idx >> 7, k = (idx & 127) * 4;
    *(f4*)&sm.hA[b][k] = *(const f4*)&er[b * NH_ + k];
  }
  __syncthreads();
  {
    int ci = tid >> 5, l = tid & 31, bg = l >> 4, kc = l & 15;
    int c = ct * 16 + ci;
    const f4* W = (const f4*)(p.out_w1 + (size_t)c * 512);
    const f4* H = (const f4*)&sm.hA[0][0];
    double acc[8] = {};
#pragma unroll
    for (int i = 0; i < 8; ++i) {
      int q = kc + 16 * i;
      f4 w = W[q];
#pragma unroll
      for (int b = 0; b < 8; ++b) acc[b] += dot4d(H[(bg * 8 + b) * (HP / 4) + q], w);
    }
#pragma unroll
    for (int b = 0; b < 8; ++b) {
      double v = acc[b];
#pragma unroll
      for (int m = 1; m <= 8; m <<= 1) v += __shfl_xor(v, m);
      if (kc == 0) sm.redH[ci][bg][b] = v;
    }
  }
  __syncthreads();
  if (tid < 256) {
    int b = tid >> 4, ci = tid & 15, c = ct * 16 + ci;
    double h1 = sm.redH[ci][b >> 3][b & 7] + (double)p.out_b1[c];
    p.h1buf[b * NH2_ + c] = (float)fmax(h1, 0.0);
  }
}

// phase B: LN(h1) -> sigmoid(h1n @ w2 + b2) -> out[b][ts]
__device__ void score_step(const Params& p, int ts) {
  const int tid = threadIdx.x;
  if (tid >= 256) return;
  int b = tid >> 4, cg = tid & 15;
  double s1 = 0, s2 = 0;
  float hv[16];
#pragma unroll
  for (int i = 0; i < 16; ++i) {
    float v = p.h1buf[b * NH2_ + cg * 16 + i];
    hv[i] = v; s1 += (double)v; s2 += (double)v * (double)v;
  }
#pragma unroll
  for (int m = 1; m <= 8; m <<= 1) { s1 += __shfl_xor(s1, m); s2 += __shfl_xor(s2, m); }
  double mu = s1 * (1.0 / NH2_), var = s2 * (1.0 / NH2_) - mu * mu, rstd = 1.0 / sqrt(var + 1e-5);
  double d = 0;
#pragma unroll
  for (int i = 0; i < 16; ++i) {
    int c = cg * 16 + i;
    d += (((double)hv[i] - mu) * rstd * p.out_ln_g[c] + (double)p.out_ln_b[c]) * (double)p.out_w2[c];
  }
#pragma unroll
  for (int m = 1; m <= 8; m <<= 1) d += __shfl_xor(d, m);
  if (cg == 0) p.out[b * NS_ + ts] = (float)sigm_d(d + (double)p.out_b2[0]);
}

// grid 144: phase A: pg 0..63 | gg 64..127 | head(t-1)+egsum-zero 128..143
//           phase B: eg 0..63 | wb 64..79 | score(t-1) 80
__global__ __launch_bounds__(512) void seq_kernel(Params p) {
  __shared__ Smem sm;
  const int bid = blockIdx.x, tid = threadIdx.x;
  for (int t = 0; t < NS_; ++t) {
    if (bid < 64) {
      pg_gg_step(p, sm, t, bid * 8, true);
    } else if (bid < 128) {
      pg_gg_step(p, sm, t, (bid - 64) * 8, false);
    } else {
      if (bid == 128 && tid < 32) p.sums[sidx(2, t & 1, tid >> 1, tid & 1)] = 0.0;
      if (t > 0) head_step(p, sm, t - 1, bid - 128);
    }
    gbar(p.bar, p.bar + 1, gridDim.x);
    if (bid < 64) {
      eg_step(p, sm, t, bid * 8);
    } else if (bid < 80) {
      wb_step(p, t, bid - 64);
    } else if (bid == 80 && t > 0) {
      score_step(p, t - 1);
    }
    gbar(p.bar, p.bar + 1, gridDim.x);
  }
  if (bid >= 128) head_step(p, sm, NS_ - 1, bid - 128);
  gbar(p.bar, p.bar + 1, gridDim.x);
  if (bid == 80) score_step(p, NS_ - 1);
}

// x-projection precompute: gix[gru][bs][row] = sum_k utt[bs][k] * wih[row][k], k<1024
// tile: 16 bs x 32 rows; x staged in LDS; W broadcast across bi-fast lanes; fp64 accum
__global__ __launch_bounds__(512) void gix_kernel(const float* utt, const float* pgw,
                                                  const float* ggw, float* gix) {
  __shared__ float xs[16][1028];
  const int tid = threadIdx.x;
  long bs0 = (long)blockIdx.x * 16;
  for (int i = tid; i < 16 * 256; i += 512) {
    int bb = i >> 8, kf = i & 255;
    *(f4*)&xs[bb][kf * 4] = *(const f4*)(utt + (bs0 + bb) * 1024 + kf * 4);
  }
  __syncthreads();
  int R = blockIdx.y * 32 + (tid >> 4);
  int bi = tid & 15;
  const float* wrow = (R < 1536) ? pgw + (size_t)R * 1536 : ggw + (size_t)(R - 1536) * 1536;
  const f4* w4 = (const f4*)wrow;
  const f4* x4 = (const f4*)&xs[bi][0];
  double acc = 0;
  for (int k = 0; k < 256; ++k) acc += dot4d(x4[k], w4[k]);
  size_t base = (R < 1536) ? 0 : (size_t)8192 * 1536;
  int r = (R < 1536) ? R : R - 1536;
  gix[base + (size_t)(bs0 + bi) * 1536 + r] = (float)acc;
}

__global__ void init_kernel(float* glob, const float* init_global, double* sums, u32* bar) {
  long stride = (long)gridDim.x * blockDim.x;
  long t0 = (long)blockIdx.x * blockDim.x + threadIdx.x;
  for (long i = t0; i < (long)NB_ * NSP_ * NH_; i += stride) {
    int sp = ((int)i >> 9) & (NSP_ - 1);
    int k = (int)i & (NH_ - 1);
    glob[i] = init_global[sp * NH_ + k];
  }
  for (long i = t0; i < 192; i += stride) sums[i] = 0.0;
  if (t0 == 0) { bar[0] = 0u; bar[1] = 0u; }
}

extern "C" void kernel_launch(void* const* d_in, const int* in_sizes, int n_in,
                              void* d_out, int out_size, void* d_ws, size_t ws_size,
                              hipStream_t stream) {
  (void)in_sizes; (void)n_in; (void)out_size;
  Params p;
  p.utt    = (const float*)d_in[0];
  p.spk    = (const int*)d_in[1];
  p.init_party   = (const float*)d_in[2];
  const float* ig = (const float*)d_in[3];
  p.init_emotion = (const float*)d_in[4];
  p.pg_wih = (const float*)d_in[5];
  p.pg_whh = (const float*)d_in[6];
  p.pg_bih = (const float*)d_in[7];
  p.pg_bhh = (const float*)d_in[8];
  p.gg_wih = (const float*)d_in[9];
  p.gg_whh = (const float*)d_in[10];
  p.gg_bih = (const float*)d_in[11];
  p.gg_bhh = (const float*)d_in[12];
  p.eg_wih = (const float*)d_in[13];
  p.eg_whh = (const float*)d_in[14];
  p.eg_bih = (const float*)d_in[15];
  p.eg_bhh = (const float*)d_in[16];
  // 17..19 attention weights: softmax over length-1 axis == 1 -> provably unused
  p.ln_g   = (const float*)d_in[20];
  p.ln_b   = (const float*)d_in[21];
  p.out_w1 = (const float*)d_in[22];
  p.out_b1 = (const float*)d_in[23];
  p.out_ln_g = (const float*)d_in[24];
  p.out_ln_b = (const float*)d_in[25];
  p.out_w2 = (const float*)d_in[26];
  p.out_b2 = (const float*)d_in[27];

  char* w = (char*)d_ws;
  auto alloc = [&](size_t bytes) { char* r = w; w += (bytes + 255) & ~(size_t)255; return r; };
  float* gix       = (float*)alloc((size_t)2 * 8192 * 1536 * 4);   // ~100.7 MB
  float* party_pre = (float*)alloc((size_t)2 * NB_ * NH_ * 4);
  float* g_new     = (float*)alloc((size_t)NB_ * NH_ * 4);
  float* e_out     = (float*)alloc((size_t)2 * NB_ * NH_ * 4);
  float* glob      = (float*)alloc((size_t)NB_ * NSP_ * NH_ * 4);
  float* h1buf     = (float*)alloc((size_t)NB_ * NH2_ * 4);
  double* sums     = (double*)alloc(192 * 8);
  u32*   bar       = (u32*)alloc(256);
  if ((size_t)(w - (char*)d_ws) > ws_size) return;  // ws too small -> loud failure (zeros)

  gix_kernel<<<dim3(512, 96), dim3(512), 0, stream>>>(p.utt, p.pg_wih, p.gg_wih, gix);
  init_kernel<<<dim3(64), dim3(256), 0, stream>>>(glob, ig, sums, bar);

  p.gixp = gix; p.gixg = gix + (size_t)8192 * 1536;
  p.party_pre = party_pre; p.g_new = g_new; p.e_out = e_out; p.glob = glob;
  p.h1buf = h1buf; p.sums = sums; p.bar = bar; p.out = (float*)d_out;

  seq_kernel<<<dim3(144), dim3(512), 0, stream>>>(p);
}

// Round 8
// 41002.539 us; speedup vs baseline: 4.2427x; 4.2427x over previous
//
#include <hip/hip_runtime.h>

typedef __attribute__((ext_vector_type(4))) float f4;
using u32 = unsigned int;

constexpr int NB_ = 16;    // batch
constexpr int NS_ = 512;   // seq len
constexpr int ND_ = 1024;  // input dim
constexpr int NH_ = 512;   // hidden
constexpr int NSP_ = 8;    // speakers
constexpr int NH2_ = 256;  // head hidden
constexpr int HP = 520;    // padded fp32 LDS row (130 f4)

struct Params {
  const float *utt;
  const float *pg_wih, *pg_whh, *gg_wih, *gg_whh, *eg_wih, *eg_whh, *out_w1;
  const float *gixp, *gixg;   // precomputed x-projections [B*S][1536] fp32
  const float *init_party, *init_emotion;
  const float *pg_bih, *pg_bhh, *gg_bih, *gg_bhh, *eg_bih, *eg_bhh;
  const float *ln_g, *ln_b, *out_b1, *out_ln_g, *out_ln_b, *out_w2, *out_b2;
  const int *spk;
  float *party_pre;  // [2][B][H] raw pg output (pre-LN), parity t&1
  float *g_new;      // [B][H]    raw gg output
  float *e_out;      // [2][B][H] raw eg output, parity t&1
  float *glob;       // [B][SP][H] post-LN (or raw init) global states
  float *h1buf;      // [B][H2] relu(e@W1+b1)
  double *sums;      // [3 groups][2 par][16 b][2] = 192 doubles
  float *out;        // [B][S]
};

__device__ __forceinline__ double sigm_d(double x) { return 1.0 / (1.0 + exp(-x)); }
__device__ __forceinline__ int sidx(int g, int par, int b, int c) {
  return ((g * 2 + par) * 16 + b) * 2 + c;
}
__device__ __forceinline__ double dot4d(f4 a, f4 w) {
  return ((double)a.x * w.x + (double)a.y * w.y) + ((double)a.z * w.z + (double)a.w * w.w);
}

// ---------------- phase A: pg (blocks 0..63) | gg (64..127) | head(t-1) (128..143) ----------------
__global__ __launch_bounds__(256, 1) void phaseA_kernel(Params p, int t) {
  __shared__ float hA[NB_][HP];
  __shared__ double red[8][NB_][4];
  __shared__ double redH[16][NB_];
  __shared__ double stats[NB_][2];
  __shared__ int spk[NB_];
  const int bid = blockIdx.x, tid = threadIdx.x;

  if (bid >= 128) {
    // zero eg sums slot for this step's parity (consumed protocol identical to R6/R7)
    if (bid == 128 && tid < 32) p.sums[sidx(2, t & 1, tid >> 1, tid & 1)] = 0.0;
    if (t < 1) return;
    int th = t - 1, ct = bid - 128;
    const float* er = p.e_out + (size_t)(th & 1) * NB_ * NH_;
    for (int idx = tid; idx < NB_ * NH_ / 4; idx += 256) {
      int b = idx >> 7, k = (idx & 127) * 4;
      *(f4*)&hA[b][k] = *(const f4*)&er[b * NH_ + k];
    }
    __syncthreads();
    {
      int ci = tid >> 4, kc = tid & 15, c = ct * 16 + ci;
      const f4* W = (const f4*)(p.out_w1 + (size_t)c * 512);
      const f4* H = (const f4*)&hA[0][0];
      double acc[NB_] = {};
#pragma unroll
      for (int i = 0; i < 8; ++i) {
        int q = kc + 16 * i;
        f4 w = W[q];
#pragma unroll
        for (int b = 0; b < NB_; ++b) acc[b] += dot4d(H[b * 130 + q], w);
      }
#pragma unroll
      for (int b = 0; b < NB_; ++b) {
        double v = acc[b];
#pragma unroll
        for (int m = 1; m <= 8; m <<= 1) v += __shfl_xor(v, m);
        if (kc == 0) redH[ci][b] = v;
      }
    }
    __syncthreads();
    {
      int b = tid >> 4, ci = tid & 15, c = ct * 16 + ci;
      double h1 = redH[ci][b] + (double)p.out_b1[c];
      p.h1buf[b * NH2_ + c] = (float)fmax(h1, 0.0);
    }
    return;
  }

  if (t >= NS_) return;
  const bool is_pg = bid < 64;
  const int jj0 = (is_pg ? bid : bid - 64) * 8;
  const float* wih = is_pg ? p.pg_wih : p.gg_wih;
  const float* whh = is_pg ? p.pg_whh : p.gg_whh;
  const float* bih = is_pg ? p.pg_bih : p.gg_bih;
  const float* bhh = is_pg ? p.pg_bhh : p.gg_bhh;
  const float* gix = is_pg ? p.gixp : p.gixg;
  const int g = is_pg ? 0 : 1;

  if (!is_pg) {
    if (tid < NB_) spk[tid] = p.spk[tid * NS_ + t];
  } else if (t > 0 && tid < NB_) {
    double s = p.sums[sidx(0, (t - 1) & 1, tid, 0)];
    double q = p.sums[sidx(0, (t - 1) & 1, tid, 1)];
    double mu = s * (1.0 / NH_), var = q * (1.0 / NH_) - mu * mu;
    stats[tid][0] = mu; stats[tid][1] = 1.0 / sqrt(var + 1e-5);
  }
  __syncthreads();

  // stage h operand (fp32 values, LN applied in fp64)
  const float* prev = p.party_pre + (size_t)((t - 1) & 1) * NB_ * NH_;
  for (int idx = tid; idx < NB_ * NH_ / 4; idx += 256) {
    int b = idx >> 7, k = (idx & 127) * 4;
    f4 v;
    if (is_pg) {
      if (t == 0) v = *(const f4*)&p.init_party[k];
      else {
        f4 pv = *(const f4*)&prev[b * NH_ + k];
        f4 g4 = *(const f4*)&p.ln_g[k], b4 = *(const f4*)&p.ln_b[k];
        double mu = stats[b][0], rs = stats[b][1];
        v.x = (float)(((double)pv.x - mu) * rs * g4.x + b4.x);
        v.y = (float)(((double)pv.y - mu) * rs * g4.y + b4.y);
        v.z = (float)(((double)pv.z - mu) * rs * g4.z + b4.z);
        v.w = (float)(((double)pv.w - mu) * rs * g4.w + b4.w);
      }
    } else {
      v = *(const f4*)&p.glob[(size_t)(b * NSP_ + spk[b]) * NH_ + k];
    }
    *(f4*)&hA[b][k] = v;
  }
  __syncthreads();

  // dot phase: 8 j per block (jj = tid>>5), 32 kc lanes, ALL 16 b in registers.
  // K=1024: i<4 -> h via wih-ctx cols [1024,1536); i>=4 -> h via whh. x-part in gix.
  {
    int jj = tid >> 5, kc = tid & 31, j = jj0 + jj;
    const f4* Wr_w = (const f4*)(wih + (size_t)j * 1536 + 1024);
    const f4* Wz_w = (const f4*)(wih + (size_t)(512 + j) * 1536 + 1024);
    const f4* Wn_w = (const f4*)(wih + (size_t)(1024 + j) * 1536 + 1024);
    const f4* Wr_h = (const f4*)(whh + (size_t)j * 512);
    const f4* Wz_h = (const f4*)(whh + (size_t)(512 + j) * 512);
    const f4* Wn_h = (const f4*)(whh + (size_t)(1024 + j) * 512);
    const f4* H = (const f4*)&hA[0][0];
    double ar[NB_] = {}, az[NB_] = {}, apn[NB_] = {}, aph[NB_] = {};
#pragma unroll
    for (int i = 0; i < 8; ++i) {
      int q = kc + 32 * i;
      f4 wr, wz, wn; int hq;
      if (i < 4) { wr = Wr_w[q]; wz = Wz_w[q]; wn = Wn_w[q]; hq = q; }
      else       { wr = Wr_h[q - 128]; wz = Wz_h[q - 128]; wn = Wn_h[q - 128]; hq = q - 128; }
#pragma unroll
      for (int b = 0; b < NB_; ++b) {
        f4 a = H[b * 130 + hq];
        ar[b] += dot4d(a, wr); az[b] += dot4d(a, wz);
        if (i < 4) apn[b] += dot4d(a, wn); else aph[b] += dot4d(a, wn);
      }
    }
#pragma unroll
    for (int b = 0; b < NB_; ++b) {
      double r = ar[b], z = az[b], pn = apn[b], ph = aph[b];
#pragma unroll
      for (int m = 1; m <= 16; m <<= 1) {
        r += __shfl_xor(r, m); z += __shfl_xor(z, m);
        pn += __shfl_xor(pn, m); ph += __shfl_xor(ph, m);
      }
      if (kc == 0) { red[jj][b][0] = r; red[jj][b][1] = z; red[jj][b][2] = pn; red[jj][b][3] = ph; }
    }
  }
  __syncthreads();

  // gate math (fp64): 128 threads = (b 16, jj 8)
  if (tid < 128) {
    int b = tid >> 3, jj = tid & 7, j = jj0 + jj;
    const double* rd = red[jj][b];
    const float* gx = gix + (size_t)(b * NS_ + t) * 1536;
    double r = sigm_d(rd[0] + (double)gx[j] + (double)bih[j] + (double)bhh[j]);
    double z = sigm_d(rd[1] + (double)gx[512 + j] + (double)bih[512 + j] + (double)bhh[512 + j]);
    double inn = rd[2] + (double)gx[1024 + j] + (double)bih[1024 + j];
    double hn  = rd[3] + (double)bhh[1024 + j];
    double n = tanh(inn + r * hn);
    double hp = (double)hA[b][j];
    double hv = (1.0 - z) * n + z * hp;
    float hf = (float)hv;
    float* dst = is_pg ? (p.party_pre + (size_t)(t & 1) * NB_ * NH_) : p.g_new;
    dst[b * NH_ + j] = hf;
    double s1 = (double)hf, s2 = (double)hf * (double)hf;
#pragma unroll
    for (int m = 1; m <= 4; m <<= 1) { s1 += __shfl_xor(s1, m); s2 += __shfl_xor(s2, m); }
    if (jj == 0) {
      atomicAdd(&p.sums[sidx(g, t & 1, b, 0)], s1);
      atomicAdd(&p.sums[sidx(g, t & 1, b, 1)], s2);
    }
  }
}

// ---------------- phase B: eg (0..63) | wb (64..79) | score(t-1) (80) ----------------
__global__ __launch_bounds__(256, 1) void phaseB_kernel(Params p, int t) {
  __shared__ float hA[NB_][HP];
  __shared__ float hB[NB_][HP];
  __shared__ double red[8][NB_][4];
  __shared__ double stats2[2][NB_][2];
  const int bid = blockIdx.x, tid = threadIdx.x;

  if (bid >= 64) {
    if (bid < 80) {
      if (t >= NS_) return;
      int b = bid - 64;
      int spv = p.spk[b * NS_ + t];
      double s = p.sums[sidx(1, t & 1, b, 0)], q = p.sums[sidx(1, t & 1, b, 1)];
      double mu = s * (1.0 / NH_), var = q * (1.0 / NH_) - mu * mu, rs = 1.0 / sqrt(var + 1e-5);
      for (int k = tid; k < NH_; k += 256)
        p.glob[(size_t)(b * NSP_ + spv) * NH_ + k] =
            (float)(((double)p.g_new[b * NH_ + k] - mu) * rs * p.ln_g[k] + p.ln_b[k]);
      if (tid == 0) {
        int par = (t + 1) & 1;
        p.sums[sidx(0, par, b, 0)] = 0.0; p.sums[sidx(0, par, b, 1)] = 0.0;
        p.sums[sidx(1, par, b, 0)] = 0.0; p.sums[sidx(1, par, b, 1)] = 0.0;
      }
    } else if (bid == 80 && t >= 1) {
      int ts = t - 1;
      int b = tid >> 4, cg = tid & 15;
      double s1 = 0, s2 = 0;
      float hv[16];
#pragma unroll
      for (int i = 0; i < 16; ++i) {
        float v = p.h1buf[b * NH2_ + cg * 16 + i];
        hv[i] = v; s1 += (double)v; s2 += (double)v * (double)v;
      }
#pragma unroll
      for (int m = 1; m <= 8; m <<= 1) { s1 += __shfl_xor(s1, m); s2 += __shfl_xor(s2, m); }
      double mu = s1 * (1.0 / NH2_), var = s2 * (1.0 / NH2_) - mu * mu, rstd = 1.0 / sqrt(var + 1e-5);
      double d = 0;
#pragma unroll
      for (int i = 0; i < 16; ++i) {
        int c = cg * 16 + i;
        d += (((double)hv[i] - mu) * rstd * p.out_ln_g[c] + (double)p.out_ln_b[c]) * (double)p.out_w2[c];
      }
#pragma unroll
      for (int m = 1; m <= 8; m <<= 1) d += __shfl_xor(d, m);
      if (cg == 0) p.out[b * NS_ + ts] = (float)sigm_d(d + (double)p.out_b2[0]);
    }
    return;
  }

  if (t >= NS_) return;
  const int jj0 = bid * 8;
  if (t > 0 && tid < NB_) {
    double s = p.sums[sidx(2, (t - 1) & 1, tid, 0)];
    double q = p.sums[sidx(2, (t - 1) & 1, tid, 1)];
    double mu = s * (1.0 / NH_), var = q * (1.0 / NH_) - mu * mu;
    stats2[0][tid][0] = mu; stats2[0][tid][1] = 1.0 / sqrt(var + 1e-5);
  }
  if (tid >= NB_ && tid < 2 * NB_) {
    int b = tid - NB_;
    double s = p.sums[sidx(1, t & 1, b, 0)];
    double q = p.sums[sidx(1, t & 1, b, 1)];
    double mu = s * (1.0 / NH_), var = q * (1.0 / NH_) - mu * mu;
    stats2[1][b][0] = mu; stats2[1][b][1] = 1.0 / sqrt(var + 1e-5);
  }
  __syncthreads();
  const float* eprev = p.e_out + (size_t)((t - 1) & 1) * NB_ * NH_;
  for (int idx = tid; idx < NB_ * NH_ / 2; idx += 256) {
    int half = idx >= NB_ * NH_ / 4;
    int r4 = idx & (NB_ * NH_ / 4 - 1);
    int b = r4 >> 7, k = (r4 & 127) * 4;
    f4 g4 = *(const f4*)&p.ln_g[k], b4 = *(const f4*)&p.ln_b[k];
    if (!half) {
      f4 v;
      if (t == 0) v = *(const f4*)&p.init_emotion[k];
      else {
        f4 pv = *(const f4*)&eprev[b * NH_ + k];
        double mu = stats2[0][b][0], rs = stats2[0][b][1];
        v.x = (float)(((double)pv.x - mu) * rs * g4.x + b4.x);
        v.y = (float)(((double)pv.y - mu) * rs * g4.y + b4.y);
        v.z = (float)(((double)pv.z - mu) * rs * g4.z + b4.z);
        v.w = (float)(((double)pv.w - mu) * rs * g4.w + b4.w);
      }
      *(f4*)&hA[b][k] = v;
    } else {
      f4 pv = *(const f4*)&p.g_new[b * NH_ + k];
      double mu = stats2[1][b][0], rs = stats2[1][b][1];
      f4 v;
      v.x = (float)(((double)pv.x - mu) * rs * g4.x + b4.x);
      v.y = (float)(((double)pv.y - mu) * rs * g4.y + b4.y);
      v.z = (float)(((double)pv.z - mu) * rs * g4.z + b4.z);
      v.w = (float)(((double)pv.w - mu) * rs * g4.w + b4.w);
      *(f4*)&hB[b][k] = v;
    }
  }
  __syncthreads();
  // K=1536: i<4 emo(hA)/wih; 4<=i<8 spk(hB)/wih; i>=8 emo(hA)/whh
  {
    int jj = tid >> 5, kc = tid & 31, j = jj0 + jj;
    const f4* Wr_w = (const f4*)(p.eg_wih + (size_t)j * 1024);
    const f4* Wz_w = (const f4*)(p.eg_wih + (size_t)(512 + j) * 1024);
    const f4* Wn_w = (const f4*)(p.eg_wih + (size_t)(1024 + j) * 1024);
    const f4* Wr_h = (const f4*)(p.eg_whh + (size_t)j * 512);
    const f4* Wz_h = (const f4*)(p.eg_whh + (size_t)(512 + j) * 512);
    const f4* Wn_h = (const f4*)(p.eg_whh + (size_t)(1024 + j) * 512);
    const f4* HA = (const f4*)&hA[0][0];
    const f4* HB = (const f4*)&hB[0][0];
    double ar[NB_] = {}, az[NB_] = {}, apn[NB_] = {}, aph[NB_] = {};
#pragma unroll
    for (int i = 0; i < 12; ++i) {
      int q = kc + 32 * i;
      f4 wr, wz, wn; const f4* Ab; int hq;
      if (i < 8) { wr = Wr_w[q]; wz = Wz_w[q]; wn = Wn_w[q]; }
      else       { wr = Wr_h[q - 256]; wz = Wz_h[q - 256]; wn = Wn_h[q - 256]; }
      if (i < 4)      { Ab = HA; hq = q; }
      else if (i < 8) { Ab = HB; hq = q - 128; }
      else            { Ab = HA; hq = q - 256; }
#pragma unroll
      for (int b = 0; b < NB_; ++b) {
        f4 a = Ab[b * 130 + hq];
        ar[b] += dot4d(a, wr); az[b] += dot4d(a, wz);
        if (i < 8) apn[b] += dot4d(a, wn); else aph[b] += dot4d(a, wn);
      }
    }
#pragma unroll
    for (int b = 0; b < NB_; ++b) {
      double r = ar[b], z = az[b], pn = apn[b], ph = aph[b];
#pragma unroll
      for (int m = 1; m <= 16; m <<= 1) {
        r += __shfl_xor(r, m); z += __shfl_xor(z, m);
        pn += __shfl_xor(pn, m); ph += __shfl_xor(ph, m);
      }
      if (kc == 0) { red[jj][b][0] = r; red[jj][b][1] = z; red[jj][b][2] = pn; red[jj][b][3] = ph; }
    }
  }
  __syncthreads();
  if (tid < 128) {
    int b = tid >> 3, jj = tid & 7, j = jj0 + jj;
    const double* rd = red[jj][b];
    double r = sigm_d(rd[0] + (double)p.eg_bih[j] + (double)p.eg_bhh[j]);
    double z = sigm_d(rd[1] + (double)p.eg_bih[512 + j] + (double)p.eg_bhh[512 + j]);
    double inn = rd[2] + (double)p.eg_bih[1024 + j];
    double hn  = rd[3] + (double)p.eg_bhh[1024 + j];
    double n = tanh(inn + r * hn);
    double hp = (double)hA[b][j];
    double hv = (1.0 - z) * n + z * hp;
    float hf = (float)hv;
    p.e_out[(size_t)(t & 1) * NB_ * NH_ + b * NH_ + j] = hf;
    double s1 = (double)hf, s2 = (double)hf * (double)hf;
#pragma unroll
    for (int m = 1; m <= 4; m <<= 1) { s1 += __shfl_xor(s1, m); s2 += __shfl_xor(s2, m); }
    if (jj == 0) {
      atomicAdd(&p.sums[sidx(2, t & 1, b, 0)], s1);
      atomicAdd(&p.sums[sidx(2, t & 1, b, 1)], s2);
    }
  }
}

// x-projection precompute: gix[gru][bs][row] = sum_k utt[bs][k] * wih[row][k], k<1024 (fp64 accum)
__global__ __launch_bounds__(512) void gix_kernel(const float* utt, const float* pgw,
                                                  const float* ggw, float* gix) {
  __shared__ float xs[16][1028];
  const int tid = threadIdx.x;
  long bs0 = (long)blockIdx.x * 16;
  for (int i = tid; i < 16 * 256; i += 512) {
    int bb = i >> 8, kf = i & 255;
    *(f4*)&xs[bb][kf * 4] = *(const f4*)(utt + (bs0 + bb) * 1024 + kf * 4);
  }
  __syncthreads();
  int R = blockIdx.y * 32 + (tid >> 4);
  int bi = tid & 15;
  const float* wrow = (R < 1536) ? pgw + (size_t)R * 1536 : ggw + (size_t)(R - 1536) * 1536;
  const f4* w4 = (const f4*)wrow;
  const f4* x4 = (const f4*)&xs[bi][0];
  double acc = 0;
  for (int k = 0; k < 256; ++k) acc += dot4d(x4[k], w4[k]);
  size_t base = (R < 1536) ? 0 : (size_t)8192 * 1536;
  int r = (R < 1536) ? R : R - 1536;
  gix[base + (size_t)(bs0 + bi) * 1536 + r] = (float)acc;
}

__global__ void init_kernel(float* glob, const float* init_global, double* sums) {
  long stride = (long)gridDim.x * blockDim.x;
  long t0 = (long)blockIdx.x * blockDim.x + threadIdx.x;
  for (long i = t0; i < (long)NB_ * NSP_ * NH_; i += stride) {
    int sp = ((int)i >> 9) & (NSP_ - 1);
    int k = (int)i & (NH_ - 1);
    glob[i] = init_global[sp * NH_ + k];
  }
  for (long i = t0; i < 192; i += stride) sums[i] = 0.0;
}

extern "C" void kernel_launch(void* const* d_in, const int* in_sizes, int n_in,
                              void* d_out, int out_size, void* d_ws, size_t ws_size,
                              hipStream_t stream) {
  (void)in_sizes; (void)n_in; (void)out_size;
  Params p;
  p.utt    = (const float*)d_in[0];
  p.spk    = (const int*)d_in[1];
  p.init_party   = (const float*)d_in[2];
  const float* ig = (const float*)d_in[3];
  p.init_emotion = (const float*)d_in[4];
  p.pg_wih = (const float*)d_in[5];
  p.pg_whh = (const float*)d_in[6];
  p.pg_bih = (const float*)d_in[7];
  p.pg_bhh = (const float*)d_in[8];
  p.gg_wih = (const float*)d_in[9];
  p.gg_whh = (const float*)d_in[10];
  p.gg_bih = (const float*)d_in[11];
  p.gg_bhh = (const float*)d_in[12];
  p.eg_wih = (const float*)d_in[13];
  p.eg_whh = (const float*)d_in[14];
  p.eg_bih = (const float*)d_in[15];
  p.eg_bhh = (const float*)d_in[16];
  // 17..19 attention weights: softmax over length-1 axis == 1 -> provably unused
  p.ln_g   = (const float*)d_in[20];
  p.ln_b   = (const float*)d_in[21];
  p.out_w1 = (const float*)d_in[22];
  p.out_b1 = (const float*)d_in[23];
  p.out_ln_g = (const float*)d_in[24];
  p.out_ln_b = (const float*)d_in[25];
  p.out_w2 = (const float*)d_in[26];
  p.out_b2 = (const float*)d_in[27];

  char* w = (char*)d_ws;
  auto alloc = [&](size_t bytes) { char* r = w; w += (bytes + 255) & ~(size_t)255; return r; };
  float* gix       = (float*)alloc((size_t)2 * 8192 * 1536 * 4);   // ~100.7 MB
  float* party_pre = (float*)alloc((size_t)2 * NB_ * NH_ * 4);
  float* g_new     = (float*)alloc((size_t)NB_ * NH_ * 4);
  float* e_out     = (float*)alloc((size_t)2 * NB_ * NH_ * 4);
  float* glob      = (float*)alloc((size_t)NB_ * NSP_ * NH_ * 4);
  float* h1buf     = (float*)alloc((size_t)NB_ * NH2_ * 4);
  double* sums     = (double*)alloc(192 * 8);
  if ((size_t)(w - (char*)d_ws) > ws_size) return;  // ws too small -> loud failure (zeros)

  gix_kernel<<<dim3(512, 96), dim3(512), 0, stream>>>(p.utt, p.pg_wih, p.gg_wih, gix);
  init_kernel<<<dim3(64), dim3(256), 0, stream>>>(glob, ig, sums);

  p.gixp = gix; p.gixg = gix + (size_t)8192 * 1536;
  p.party_pre = party_pre; p.g_new = g_new; p.e_out = e_out; p.glob = glob;
  p.h1buf = h1buf; p.sums = sums; p.out = (float*)d_out;

  // dispatch chain: ordering via stream, no device barriers/fences.
  // t = 0..NS_: phaseA(t) = pg(t)|gg(t)|head(t-1); phaseB(t) = eg(t)|wb(t)|score(t-1).
  // At t = NS_ only the lagged parts (head(NS-1), score(NS-1)) execute.
  for (int t = 0; t <= NS_; ++t) {
    phaseA_kernel<<<dim3(144), dim3(256), 0, stream>>>(p, t);
    phaseB_kernel<<<dim3(81), dim3(256), 0, stream>>>(p, t);
  }
}

// Round 9
// 30452.887 us; speedup vs baseline: 5.7125x; 1.3464x over previous
//
#include <hip/hip_runtime.h>

typedef __attribute__((ext_vector_type(4))) float f4;
using u32 = unsigned int;

constexpr int NB_ = 16;    // batch
constexpr int NS_ = 512;   // seq len
constexpr int ND_ = 1024;  // input dim
constexpr int NH_ = 512;   // hidden
constexpr int NSP_ = 8;    // speakers
constexpr int NH2_ = 256;  // head hidden
constexpr int HP = 520;    // padded fp32 LDS row (130 f4)

struct Params {
  const float *utt;
  const float *pg_wih, *pg_whh, *gg_wih, *gg_whh, *eg_wih, *eg_whh, *out_w1;
  const float *gixp, *gixg;   // precomputed x-projections [B*S][1536] fp32
  const float *init_party, *init_emotion;
  const float *pg_bih, *pg_bhh, *gg_bih, *gg_bhh, *eg_bih, *eg_bhh;
  const float *ln_g, *ln_b, *out_b1, *out_ln_g, *out_ln_b, *out_w2, *out_b2;
  const int *spk;
  float *party_pre;  // [2][B][H] raw pg output (pre-LN), parity t&1
  float *g_new;      // [2][B][H] raw gg output, parity t&1
  float *e_out;      // [2][B][H] raw eg output, parity te&1
  float *glob;       // [B][SP][H] post-LN (or raw init) global states
  float *h1buf;      // [2][B][H2] relu(e@W1+b1), parity th&1
  double *sums;      // [3 groups][4 slots][16 b][2] = 384 doubles
  float *out;        // [B][S]
};

__device__ __forceinline__ double sigm_d(double x) { return 1.0 / (1.0 + exp(-x)); }
__device__ __forceinline__ int sidx(int g, int slot, int b, int c) {
  return ((g * 4 + slot) * 16 + b) * 2 + c;
}
__device__ __forceinline__ double dot4d(f4 a, f4 w) {
  return ((double)a.x * w.x + (double)a.y * w.y) + ((double)a.z * w.z + (double)a.w * w.w);
}

// One dispatch per step t (software-pipelined):
//   bid 0..63    pg(t)        t < NS
//   bid 64..127  gg(t)        t < NS   (speaker-substitution; no glob race)
//   bid 128..191 eg(t-1)      1 <= t <= NS
//   bid 192..207 wb(t-1)+zero  (zeroing all t; writeback 1 <= t <= NS)
//   bid 208..223 head(t-2)    2 <= t <= NS+1
//   bid 224      score(t-3)   3 <= t <= NS+2
__global__ __launch_bounds__(256, 1) void step_kernel(Params p, int t) {
  __shared__ float hA[NB_][HP];
  __shared__ float hB[NB_][HP];
  __shared__ double red[8][NB_][4];
  __shared__ double redH[16][NB_];
  __shared__ double stats[NB_][2];
  __shared__ double stats2[NB_][2];
  __shared__ int spk[NB_], spkp[NB_];
  const int bid = blockIdx.x, tid = threadIdx.x;

  // ---------------- wb + sums zeroing (blocks 192..207) ----------------
  if (bid >= 192 && bid < 208) {
    int b = bid - 192;
    if (tid == 0) {
      // rotate-zero: group0/1 slot (t+2)&3, group2 slot (t+1)&3 (distinct from all live slots)
      p.sums[sidx(0, (t + 2) & 3, b, 0)] = 0.0; p.sums[sidx(0, (t + 2) & 3, b, 1)] = 0.0;
      p.sums[sidx(1, (t + 2) & 3, b, 0)] = 0.0; p.sums[sidx(1, (t + 2) & 3, b, 1)] = 0.0;
      p.sums[sidx(2, (t + 1) & 3, b, 0)] = 0.0; p.sums[sidx(2, (t + 1) & 3, b, 1)] = 0.0;
    }
    if (t >= 1 && t <= NS_) {
      int tw = t - 1;
      int spv = p.spk[b * NS_ + tw];
      double s = p.sums[sidx(1, tw & 3, b, 0)], q = p.sums[sidx(1, tw & 3, b, 1)];
      double mu = s * (1.0 / NH_), var = q * (1.0 / NH_) - mu * mu, rs = 1.0 / sqrt(var + 1e-5);
      const float* gsrc = p.g_new + (size_t)(tw & 1) * NB_ * NH_;
      for (int k = tid; k < NH_; k += 256)
        p.glob[(size_t)(b * NSP_ + spv) * NH_ + k] =
            (float)(((double)gsrc[b * NH_ + k] - mu) * rs * p.ln_g[k] + p.ln_b[k]);
    }
    return;
  }

  // ---------------- head(t-2) (blocks 208..223) ----------------
  if (bid >= 208 && bid < 224) {
    if (t < 2 || t > NS_ + 1) return;
    int th = t - 2, ct = bid - 208;
    const float* er = p.e_out + (size_t)(th & 1) * NB_ * NH_;
    for (int idx = tid; idx < NB_ * NH_ / 4; idx += 256) {
      int b = idx >> 7, k = (idx & 127) * 4;
      *(f4*)&hA[b][k] = *(const f4*)&er[b * NH_ + k];
    }
    __syncthreads();
    {
      int ci = tid >> 4, kc = tid & 15, c = ct * 16 + ci;
      const f4* W = (const f4*)(p.out_w1 + (size_t)c * 512);
      const f4* H = (const f4*)&hA[0][0];
      double acc[NB_] = {};
#pragma unroll
      for (int i = 0; i < 8; ++i) {
        int q = kc + 16 * i;
        f4 w = W[q];
#pragma unroll
        for (int b = 0; b < NB_; ++b) acc[b] += dot4d(H[b * 130 + q], w);
      }
#pragma unroll
      for (int b = 0; b < NB_; ++b) {
        double v = acc[b];
#pragma unroll
        for (int m = 1; m <= 8; m <<= 1) v += __shfl_xor(v, m);
        if (kc == 0) redH[ci][b] = v;
      }
    }
    __syncthreads();
    {
      int b = tid >> 4, ci = tid & 15, c = ct * 16 + ci;
      double h1 = redH[ci][b] + (double)p.out_b1[c];
      p.h1buf[(size_t)(th & 1) * NB_ * NH2_ + b * NH2_ + c] = (float)fmax(h1, 0.0);
    }
    return;
  }

  // ---------------- score(t-3) (block 224) ----------------
  if (bid == 224) {
    if (t < 3 || t > NS_ + 2) return;
    int ts = t - 3;
    int b = tid >> 4, cg = tid & 15;
    const float* h1p = p.h1buf + (size_t)(ts & 1) * NB_ * NH2_;
    double s1 = 0, s2 = 0;
    float hv[16];
#pragma unroll
    for (int i = 0; i < 16; ++i) {
      float v = h1p[b * NH2_ + cg * 16 + i];
      hv[i] = v; s1 += (double)v; s2 += (double)v * (double)v;
    }
#pragma unroll
    for (int m = 1; m <= 8; m <<= 1) { s1 += __shfl_xor(s1, m); s2 += __shfl_xor(s2, m); }
    double mu = s1 * (1.0 / NH2_), var = s2 * (1.0 / NH2_) - mu * mu, rstd = 1.0 / sqrt(var + 1e-5);
    double d = 0;
#pragma unroll
    for (int i = 0; i < 16; ++i) {
      int c = cg * 16 + i;
      d += (((double)hv[i] - mu) * rstd * p.out_ln_g[c] + (double)p.out_ln_b[c]) * (double)p.out_w2[c];
    }
#pragma unroll
    for (int m = 1; m <= 8; m <<= 1) d += __shfl_xor(d, m);
    if (cg == 0) p.out[b * NS_ + ts] = (float)sigm_d(d + (double)p.out_b2[0]);
    return;
  }

  // ---------------- eg(t-1) (blocks 128..191) ----------------
  if (bid >= 128) {
    if (t < 1 || t > NS_) return;
    const int te = t - 1;
    const int jj0 = (bid - 128) * 8;
    if (te > 0 && tid < NB_) {
      double s = p.sums[sidx(2, (te - 1) & 3, tid, 0)];
      double q = p.sums[sidx(2, (te - 1) & 3, tid, 1)];
      double mu = s * (1.0 / NH_), var = q * (1.0 / NH_) - mu * mu;
      stats[tid][0] = mu; stats[tid][1] = 1.0 / sqrt(var + 1e-5);
    }
    if (tid >= NB_ && tid < 2 * NB_) {
      int b = tid - NB_;
      double s = p.sums[sidx(1, te & 3, b, 0)];
      double q = p.sums[sidx(1, te & 3, b, 1)];
      double mu = s * (1.0 / NH_), var = q * (1.0 / NH_) - mu * mu;
      stats2[b][0] = mu; stats2[b][1] = 1.0 / sqrt(var + 1e-5);
    }
    __syncthreads();
    const float* eprev = p.e_out + (size_t)((te - 1) & 1) * NB_ * NH_;
    const float* gcur  = p.g_new + (size_t)(te & 1) * NB_ * NH_;
    for (int idx = tid; idx < NB_ * NH_ / 2; idx += 256) {
      int half = idx >= NB_ * NH_ / 4;
      int r4 = idx & (NB_ * NH_ / 4 - 1);
      int b = r4 >> 7, k = (r4 & 127) * 4;
      f4 g4 = *(const f4*)&p.ln_g[k], b4 = *(const f4*)&p.ln_b[k];
      if (!half) {
        f4 v;
        if (te == 0) v = *(const f4*)&p.init_emotion[k];
        else {
          f4 pv = *(const f4*)&eprev[b * NH_ + k];
          double mu = stats[b][0], rs = stats[b][1];
          v.x = (float)(((double)pv.x - mu) * rs * g4.x + b4.x);
          v.y = (float)(((double)pv.y - mu) * rs * g4.y + b4.y);
          v.z = (float)(((double)pv.z - mu) * rs * g4.z + b4.z);
          v.w = (float)(((double)pv.w - mu) * rs * g4.w + b4.w);
        }
        *(f4*)&hA[b][k] = v;
      } else {
        f4 pv = *(const f4*)&gcur[b * NH_ + k];
        double mu = stats2[b][0], rs = stats2[b][1];
        f4 v;
        v.x = (float)(((double)pv.x - mu) * rs * g4.x + b4.x);
        v.y = (float)(((double)pv.y - mu) * rs * g4.y + b4.y);
        v.z = (float)(((double)pv.z - mu) * rs * g4.z + b4.z);
        v.w = (float)(((double)pv.w - mu) * rs * g4.w + b4.w);
        *(f4*)&hB[b][k] = v;
      }
    }
    __syncthreads();
    // K=1536: i<4 emo(hA)/wih; 4<=i<8 spk(hB)/wih; i>=8 emo(hA)/whh
    {
      int jj = tid >> 5, kc = tid & 31, j = jj0 + jj;
      const f4* Wr_w = (const f4*)(p.eg_wih + (size_t)j * 1024);
      const f4* Wz_w = (const f4*)(p.eg_wih + (size_t)(512 + j) * 1024);
      const f4* Wn_w = (const f4*)(p.eg_wih + (size_t)(1024 + j) * 1024);
      const f4* Wr_h = (const f4*)(p.eg_whh + (size_t)j * 512);
      const f4* Wz_h = (const f4*)(p.eg_whh + (size_t)(512 + j) * 512);
      const f4* Wn_h = (const f4*)(p.eg_whh + (size_t)(1024 + j) * 512);
      const f4* HA = (const f4*)&hA[0][0];
      const f4* HB = (const f4*)&hB[0][0];
      double ar[NB_] = {}, az[NB_] = {}, apn[NB_] = {}, aph[NB_] = {};
#pragma unroll
      for (int i = 0; i < 12; ++i) {
        int q = kc + 32 * i;
        f4 wr, wz, wn; const f4* Ab; int hq;
        if (i < 8) { wr = Wr_w[q]; wz = Wz_w[q]; wn = Wn_w[q]; }
        else       { wr = Wr_h[q - 256]; wz = Wz_h[q - 256]; wn = Wn_h[q - 256]; }
        if (i < 4)      { Ab = HA; hq = q; }
        else if (i < 8) { Ab = HB; hq = q - 128; }
        else            { Ab = HA; hq = q - 256; }
#pragma unroll
        for (int b = 0; b < NB_; ++b) {
          f4 a = Ab[b * 130 + hq];
          ar[b] += dot4d(a, wr); az[b] += dot4d(a, wz);
          if (i < 8) apn[b] += dot4d(a, wn); else aph[b] += dot4d(a, wn);
        }
      }
#pragma unroll
      for (int b = 0; b < NB_; ++b) {
        double r = ar[b], z = az[b], pn = apn[b], ph = aph[b];
#pragma unroll
        for (int m = 1; m <= 16; m <<= 1) {
          r += __shfl_xor(r, m); z += __shfl_xor(z, m);
          pn += __shfl_xor(pn, m); ph += __shfl_xor(ph, m);
        }
        if (kc == 0) { red[jj][b][0] = r; red[jj][b][1] = z; red[jj][b][2] = pn; red[jj][b][3] = ph; }
      }
    }
    __syncthreads();
    if (tid < 128) {
      int b = tid >> 3, jj = tid & 7, j = jj0 + jj;
      const double* rd = red[jj][b];
      double r = sigm_d(rd[0] + (double)p.eg_bih[j] + (double)p.eg_bhh[j]);
      double z = sigm_d(rd[1] + (double)p.eg_bih[512 + j] + (double)p.eg_bhh[512 + j]);
      double inn = rd[2] + (double)p.eg_bih[1024 + j];
      double hn  = rd[3] + (double)p.eg_bhh[1024 + j];
      double n = tanh(inn + r * hn);
      double hp = (double)hA[b][j];
      double hv = (1.0 - z) * n + z * hp;
      float hf = (float)hv;
      p.e_out[(size_t)(te & 1) * NB_ * NH_ + b * NH_ + j] = hf;
      double s1 = (double)hf, s2 = (double)hf * (double)hf;
#pragma unroll
      for (int m = 1; m <= 4; m <<= 1) { s1 += __shfl_xor(s1, m); s2 += __shfl_xor(s2, m); }
      if (jj == 0) {
        atomicAdd(&p.sums[sidx(2, te & 3, b, 0)], s1);
        atomicAdd(&p.sums[sidx(2, te & 3, b, 1)], s2);
      }
    }
    return;
  }

  // ---------------- pg(t) (0..63) | gg(t) (64..127) ----------------
  if (t >= NS_) return;
  const bool is_pg = bid < 64;
  const int jj0 = (is_pg ? bid : bid - 64) * 8;
  const float* wih = is_pg ? p.pg_wih : p.gg_wih;
  const float* whh = is_pg ? p.pg_whh : p.gg_whh;
  const float* bih = is_pg ? p.pg_bih : p.gg_bih;
  const float* bhh = is_pg ? p.pg_bhh : p.gg_bhh;
  const float* gix = is_pg ? p.gixp : p.gixg;
  const int g = is_pg ? 0 : 1;

  if (!is_pg) {
    if (tid < NB_) {
      spk[tid]  = p.spk[tid * NS_ + t];
      spkp[tid] = (t > 0) ? p.spk[tid * NS_ + t - 1] : -1;
      if (t > 0) {
        double s = p.sums[sidx(1, (t - 1) & 3, tid, 0)];
        double q = p.sums[sidx(1, (t - 1) & 3, tid, 1)];
        double mu = s * (1.0 / NH_), var = q * (1.0 / NH_) - mu * mu;
        stats[tid][0] = mu; stats[tid][1] = 1.0 / sqrt(var + 1e-5);
      }
    }
  } else if (t > 0 && tid < NB_) {
    double s = p.sums[sidx(0, (t - 1) & 3, tid, 0)];
    double q = p.sums[sidx(0, (t - 1) & 3, tid, 1)];
    double mu = s * (1.0 / NH_), var = q * (1.0 / NH_) - mu * mu;
    stats[tid][0] = mu; stats[tid][1] = 1.0 / sqrt(var + 1e-5);
  }
  __syncthreads();

  // stage h operand. pg: LN(party(t-1)) or init. gg: glob[b][spk], with on-the-fly
  // substitution LN(g_new(t-1)) when spk_t == spk_{t-1} (wb(t-1) runs concurrently).
  const float* prev = p.party_pre + (size_t)((t - 1) & 1) * NB_ * NH_;
  const float* gprev = p.g_new + (size_t)((t - 1) & 1) * NB_ * NH_;
  for (int idx = tid; idx < NB_ * NH_ / 4; idx += 256) {
    int b = idx >> 7, k = (idx & 127) * 4;
    f4 v;
    if (is_pg) {
      if (t == 0) v = *(const f4*)&p.init_party[k];
      else {
        f4 pv = *(const f4*)&prev[b * NH_ + k];
        f4 g4 = *(const f4*)&p.ln_g[k], b4 = *(const f4*)&p.ln_b[k];
        double mu = stats[b][0], rs = stats[b][1];
        v.x = (float)(((double)pv.x - mu) * rs * g4.x + b4.x);
        v.y = (float)(((double)pv.y - mu) * rs * g4.y + b4.y);
        v.z = (float)(((double)pv.z - mu) * rs * g4.z + b4.z);
        v.w = (float)(((double)pv.w - mu) * rs * g4.w + b4.w);
      }
    } else {
      if (spk[b] == spkp[b]) {
        f4 pv = *(const f4*)&gprev[b * NH_ + k];
        f4 g4 = *(const f4*)&p.ln_g[k], b4 = *(const f4*)&p.ln_b[k];
        double mu = stats[b][0], rs = stats[b][1];
        v.x = (float)(((double)pv.x - mu) * rs * g4.x + b4.x);
        v.y = (float)(((double)pv.y - mu) * rs * g4.y + b4.y);
        v.z = (float)(((double)pv.z - mu) * rs * g4.z + b4.z);
        v.w = (float)(((double)pv.w - mu) * rs * g4.w + b4.w);
      } else {
        v = *(const f4*)&p.glob[(size_t)(b * NSP_ + spk[b]) * NH_ + k];
      }
    }
    *(f4*)&hA[b][k] = v;
  }
  __syncthreads();

  // dot phase: 8 j per block, 32 kc lanes, all 16 b in registers.
  // K=1024: i<4 -> h via wih-ctx cols [1024,1536); i>=4 -> h via whh. x-part in gix.
  {
    int jj = tid >> 5, kc = tid & 31, j = jj0 + jj;
    const f4* Wr_w = (const f4*)(wih + (size_t)j * 1536 + 1024);
    const f4* Wz_w = (const f4*)(wih + (size_t)(512 + j) * 1536 + 1024);
    const f4* Wn_w = (const f4*)(wih + (size_t)(1024 + j) * 1536 + 1024);
    const f4* Wr_h = (const f4*)(whh + (size_t)j * 512);
    const f4* Wz_h = (const f4*)(whh + (size_t)(512 + j) * 512);
    const f4* Wn_h = (const f4*)(whh + (size_t)(1024 + j) * 512);
    const f4* H = (const f4*)&hA[0][0];
    double ar[NB_] = {}, az[NB_] = {}, apn[NB_] = {}, aph[NB_] = {};
#pragma unroll
    for (int i = 0; i < 8; ++i) {
      int q = kc + 32 * i;
      f4 wr, wz, wn; int hq;
      if (i < 4) { wr = Wr_w[q]; wz = Wz_w[q]; wn = Wn_w[q]; hq = q; }
      else       { wr = Wr_h[q - 128]; wz = Wz_h[q - 128]; wn = Wn_h[q - 128]; hq = q - 128; }
#pragma unroll
      for (int b = 0; b < NB_; ++b) {
        f4 a = H[b * 130 + hq];
        ar[b] += dot4d(a, wr); az[b] += dot4d(a, wz);
        if (i < 4) apn[b] += dot4d(a, wn); else aph[b] += dot4d(a, wn);
      }
    }
#pragma unroll
    for (int b = 0; b < NB_; ++b) {
      double r = ar[b], z = az[b], pn = apn[b], ph = aph[b];
#pragma unroll
      for (int m = 1; m <= 16; m <<= 1) {
        r += __shfl_xor(r, m); z += __shfl_xor(z, m);
        pn += __shfl_xor(pn, m); ph += __shfl_xor(ph, m);
      }
      if (kc == 0) { red[jj][b][0] = r; red[jj][b][1] = z; red[jj][b][2] = pn; red[jj][b][3] = ph; }
    }
  }
  __syncthreads();

  // gate math (fp64): 128 threads = (b 16, jj 8)
  if (tid < 128) {
    int b = tid >> 3, jj = tid & 7, j = jj0 + jj;
    const double* rd = red[jj][b];
    const float* gx = gix + (size_t)(b * NS_ + t) * 1536;
    double r = sigm_d(rd[0] + (double)gx[j] + (double)bih[j] + (double)bhh[j]);
    double z = sigm_d(rd[1] + (double)gx[512 + j] + (double)bih[512 + j] + (double)bhh[512 + j]);
    double inn = rd[2] + (double)gx[1024 + j] + (double)bih[1024 + j];
    double hn  = rd[3] + (double)bhh[1024 + j];
    double n = tanh(inn + r * hn);
    double hp = (double)hA[b][j];
    double hv = (1.0 - z) * n + z * hp;
    float hf = (float)hv;
    float* dst = is_pg ? (p.party_pre + (size_t)(t & 1) * NB_ * NH_)
                       : (p.g_new + (size_t)(t & 1) * NB_ * NH_);
    dst[b * NH_ + j] = hf;
    double s1 = (double)hf, s2 = (double)hf * (double)hf;
#pragma unroll
    for (int m = 1; m <= 4; m <<= 1) { s1 += __shfl_xor(s1, m); s2 += __shfl_xor(s2, m); }
    if (jj == 0) {
      atomicAdd(&p.sums[sidx(g, t & 3, b, 0)], s1);
      atomicAdd(&p.sums[sidx(g, t & 3, b, 1)], s2);
    }
  }
}

// x-projection precompute: gix[gru][bs][row] = sum_k utt[bs][k] * wih[row][k], k<1024 (fp64 accum)
__global__ __launch_bounds__(512) void gix_kernel(const float* utt, const float* pgw,
                                                  const float* ggw, float* gix) {
  __shared__ float xs[16][1028];
  const int tid = threadIdx.x;
  long bs0 = (long)blockIdx.x * 16;
  for (int i = tid; i < 16 * 256; i += 512) {
    int bb = i >> 8, kf = i & 255;
    *(f4*)&xs[bb][kf * 4] = *(const f4*)(utt + (bs0 + bb) * 1024 + kf * 4);
  }
  __syncthreads();
  int R = blockIdx.y * 32 + (tid >> 4);
  int bi = tid & 15;
  const float* wrow = (R < 1536) ? pgw + (size_t)R * 1536 : ggw + (size_t)(R - 1536) * 1536;
  const f4* w4 = (const f4*)wrow;
  const f4* x4 = (const f4*)&xs[bi][0];
  double acc = 0;
  for (int k = 0; k < 256; ++k) acc += dot4d(x4[k], w4[k]);
  size_t base = (R < 1536) ? 0 : (size_t)8192 * 1536;
  int r = (R < 1536) ? R : R - 1536;
  gix[base + (size_t)(bs0 + bi) * 1536 + r] = (float)acc;
}

__global__ void init_kernel(float* glob, const float* init_global, double* sums) {
  long stride = (long)gridDim.x * blockDim.x;
  long t0 = (long)blockIdx.x * blockDim.x + threadIdx.x;
  for (long i = t0; i < (long)NB_ * NSP_ * NH_; i += stride) {
    int sp = ((int)i >> 9) & (NSP_ - 1);
    int k = (int)i & (NH_ - 1);
    glob[i] = init_global[sp * NH_ + k];
  }
  for (long i = t0; i < 384; i += stride) sums[i] = 0.0;
}

extern "C" void kernel_launch(void* const* d_in, const int* in_sizes, int n_in,
                              void* d_out, int out_size, void* d_ws, size_t ws_size,
                              hipStream_t stream) {
  (void)in_sizes; (void)n_in; (void)out_size;
  Params p;
  p.utt    = (const float*)d_in[0];
  p.spk    = (const int*)d_in[1];
  p.init_party   = (const float*)d_in[2];
  const float* ig = (const float*)d_in[3];
  p.init_emotion = (const float*)d_in[4];
  p.pg_wih = (const float*)d_in[5];
  p.pg_whh = (const float*)d_in[6];
  p.pg_bih = (const float*)d_in[7];
  p.pg_bhh = (const float*)d_in[8];
  p.gg_wih = (const float*)d_in[9];
  p.gg_whh = (const float*)d_in[10];
  p.gg_bih = (const float*)d_in[11];
  p.gg_bhh = (const float*)d_in[12];
  p.eg_wih = (const float*)d_in[13];
  p.eg_whh = (const float*)d_in[14];
  p.eg_bih = (const float*)d_in[15];
  p.eg_bhh = (const float*)d_in[16];
  // 17..19 attention weights: softmax over length-1 axis == 1 -> provably unused
  p.ln_g   = (const float*)d_in[20];
  p.ln_b   = (const float*)d_in[21];
  p.out_w1 = (const float*)d_in[22];
  p.out_b1 = (const float*)d_in[23];
  p.out_ln_g = (const float*)d_in[24];
  p.out_ln_b = (const float*)d_in[25];
  p.out_w2 = (const float*)d_in[26];
  p.out_b2 = (const float*)d_in[27];

  char* w = (char*)d_ws;
  auto alloc = [&](size_t bytes) { char* r = w; w += (bytes + 255) & ~(size_t)255; return r; };
  float* gix       = (float*)alloc((size_t)2 * 8192 * 1536 * 4);   // ~100.7 MB
  float* party_pre = (float*)alloc((size_t)2 * NB_ * NH_ * 4);
  float* g_new     = (float*)alloc((size_t)2 * NB_ * NH_ * 4);
  float* e_out     = (float*)alloc((size_t)2 * NB_ * NH_ * 4);
  float* glob      = (float*)alloc((size_t)NB_ * NSP_ * NH_ * 4);
  float* h1buf     = (float*)alloc((size_t)2 * NB_ * NH2_ * 4);
  double* sums     = (double*)alloc(384 * 8);
  if ((size_t)(w - (char*)d_ws) > ws_size) return;  // ws too small -> loud failure (zeros)

  gix_kernel<<<dim3(512, 96), dim3(512), 0, stream>>>(p.utt, p.pg_wih, p.gg_wih, gix);
  init_kernel<<<dim3(64), dim3(256), 0, stream>>>(glob, ig, sums);

  p.gixp = gix; p.gixg = gix + (size_t)8192 * 1536;
  p.party_pre = party_pre; p.g_new = g_new; p.e_out = e_out; p.glob = glob;
  p.h1buf = h1buf; p.sums = sums; p.out = (float*)d_out;

  // one dispatch per pipelined step; tail drains eg/head/score
  for (int t = 0; t <= NS_ + 2; ++t) {
    step_kernel<<<dim3(225), dim3(256), 0, stream>>>(p, t);
  }
}